// Round 3
// baseline (562220.996 us; speedup 1.0000x reference)
//
#include <hip/hip_runtime.h>

// Persistent-LSTM, round 7: producer/consumer XCD split (R6 compile-fixed).
//   Consumers (XCDs 0-3, 4 teams x 64 WGs x 128 thr): h-recurrence only.
//   Producers (XCDs 4-7, 256 blocks): compute xpart = bias + x_t @ Wih^T,
//   1:1 wave mapping to consumer waves, stream f32x4 planes into a WIN-deep
//   MALL ring (sc0 sc1 stores + amortized agent flags).
//
//   R6 failed to compile: float4 (struct) can't bind to "v" asm constraints.
//   R7 uses f32x4 ext-vector for all dwordx4 asm operands. Design unchanged:
//   R5 proved sync scope isn't the bottleneck (FETCH 399->62MB, dur flat);
//   R7 removes the x-path (16 scatter loads + ~400 VALU converts + 24 MFMA)
//   from the consumer's serial chain and cuts consumer weights 192->128
//   VGPRs (h hi/lo fully resident). Producers pace off agent-scope flagsB;
//   consumers pace off xpflags (amortized, producer runs >=WIN ahead).
//   Fallback: win==0 -> R5 inline path, producers exit immediately.

#define NB 64
#define NS 512
#define ND 256
#define NH 512
#define FLAG_MAGIC 0x41000000
#define PLANE_ELEMS (NB * NH)   // 32768 elems, 64 KiB/plane
#define NWORK 256               // consumer blocks (4 teams x 64 WGs)

#define LD_AGENT(p)    __hip_atomic_load((p), __ATOMIC_RELAXED, __HIP_MEMORY_SCOPE_AGENT)
#define ST_AGENT(p,v)  __hip_atomic_store((p), (v), __ATOMIC_RELAXED, __HIP_MEMORY_SCOPE_AGENT)
#define ST_WG(p,v)     __hip_atomic_store((p), (v), __ATOMIC_RELAXED, __HIP_MEMORY_SCOPE_WORKGROUP)
#define MFMA(a,b,c)    __builtin_amdgcn_mfma_f32_16x16x32_bf16((a),(b),(c),0,0,0)

typedef __bf16 bf16x8 __attribute__((ext_vector_type(8)));
typedef float  f32x4  __attribute__((ext_vector_type(4)));

union Frag {
  bf16x8 v;
  unsigned long long u[2];
  __bf16 e[8];
};

__device__ __forceinline__ float bf2f(__bf16 b) {
  unsigned short us = __builtin_bit_cast(unsigned short, b);
  unsigned int ui = ((unsigned int)us) << 16;
  return __builtin_bit_cast(float, ui);
}

__device__ __forceinline__ void hilo8(const float* vals, Frag& fh, Frag& fl) {
#pragma unroll
  for (int j = 0; j < 8; ++j) {
    __bf16 hi = (__bf16)vals[j];
    float r = vals[j] - bf2f(hi);
    fh.e[j] = hi;
    fl.e[j] = (__bf16)r;
  }
}

__device__ __forceinline__ float fsigmoid(float x) {
  return 1.0f / (1.0f + __expf(-x));
}
__device__ __forceinline__ float ftanh(float x) {
  float t = fminf(fmaxf(2.0f * x, -30.0f), 30.0f);
  float e = __expf(t);
  return (e - 1.0f) / (e + 1.0f);
}

// L1-bypass load served by the XCD L2.
__device__ __forceinline__ int poll_sc0(const int* p) {
  int v;
  asm volatile("global_load_dword %0, %1, off sc0\n\ts_waitcnt vmcnt(0)"
               : "=&v"(v) : "v"(p) : "memory");
  return v;
}

// ---------------------------------------------------------------------------
// Producer: x-projection stream for one consumer wave
// ---------------------------------------------------------------------------
__device__ __forceinline__ void run_producer(
    const float* __restrict__ x, const float* __restrict__ Wih,
    const float* __restrict__ bih, const float* __restrict__ bhh,
    int* flagsB_wg, int* xpflag_p, f32x4* ringW, int win,
    int lane, int quad, int myb, int myh, int rA)
{
  // x-part weights (K = 0..255), compensated hi/lo
  bf16x8 Ahi[8], Alo[8];
  {
    const float* wi = Wih + rA * ND;
#pragma unroll
    for (int c = 0; c < 8; ++c) {
      int k0 = c * 32 + quad * 8;
      float4 f0 = *(const float4*)(wi + k0);
      float4 f1 = *(const float4*)(wi + k0 + 4);
      float vals[8] = {f0.x, f0.y, f0.z, f0.w, f1.x, f1.y, f1.z, f1.w};
      Frag fh, fl;
      hilo8(vals, fh, fl);
      Ahi[c] = fh.v;
      Alo[c] = fl.v;
    }
  }
  float bias[4];
#pragma unroll
  for (int g = 0; g < 4; ++g)
    bias[g] = bih[g * NH + myh] + bhh[g * NH + myh];

  const int mask = win - 1;
  int seen = -1;   // cached consumer progress (steps completed)
  const float* xr0 = x + myb * NS * ND + quad * 8;

  float4 xf[16];
#pragma unroll
  for (int c = 0; c < 8; ++c) {
    xf[2 * c]     = *(const float4*)(xr0 + 32 * c);
    xf[2 * c + 1] = *(const float4*)(xr0 + 32 * c + 4);
  }

#pragma unroll 1
  for (int t = 0; t < NS; ++t) {
    // convert current x row (frees xf), then prefetch next row
    Frag bh[8], bl[8];
#pragma unroll
    for (int c = 0; c < 8; ++c) {
      float vals[8] = {xf[2*c].x, xf[2*c].y, xf[2*c].z, xf[2*c].w,
                       xf[2*c+1].x, xf[2*c+1].y, xf[2*c+1].z, xf[2*c+1].w};
      hilo8(vals, bh[c], bl[c]);
    }
    if (t + 1 < NS) {
      const float* xr = xr0 + (t + 1) * ND;
#pragma unroll
      for (int c = 0; c < 8; ++c) {
        xf[2 * c]     = *(const float4*)(xr + 32 * c);
        xf[2 * c + 1] = *(const float4*)(xr + 32 * c + 4);
      }
    }
    f32x4 a_hh = {bias[0], bias[1], bias[2], bias[3]};
    f32x4 a_hl = {0.f, 0.f, 0.f, 0.f};
    f32x4 a_lh = {0.f, 0.f, 0.f, 0.f};
#pragma unroll
    for (int c = 0; c < 8; ++c) {
      a_hh = MFMA(Ahi[c], bh[c].v, a_hh);
      a_hl = MFMA(Ahi[c], bl[c].v, a_hl);
      a_lh = MFMA(Alo[c], bh[c].v, a_lh);
    }

    // pacing: slot (t & mask) must be consumed (consumer done step t-win+1)
    if (t >= win) {
      int need = t - win + 1;
      if (seen < need) {
        while (true) {
          int f = LD_AGENT(flagsB_wg);
          unsigned int d = (unsigned int)(f - FLAG_MAGIC);
          if (d <= 512u && (int)d >= need) { seen = (int)d; break; }
          __builtin_amdgcn_s_sleep(1);
        }
      }
    }

    f32x4 v;
    v[0] = a_hh[0] + a_hl[0] + a_lh[0];
    v[1] = a_hh[1] + a_hl[1] + a_lh[1];
    v[2] = a_hh[2] + a_hl[2] + a_lh[2];
    v[3] = a_hh[3] + a_hl[3] + a_lh[3];
    f32x4* dst = ringW + (size_t)(t & mask) * 64 + lane;
    // MALL-visible store (bypass local L1/L2): consumers are on another XCD
    asm volatile("global_store_dwordx4 %0, %1, off sc0 sc1"
                 :: "v"(dst), "v"(v) : "memory");

    if ((t & 3) == 3 || t == NS - 1) {      // amortized progress flag
      asm volatile("s_waitcnt vmcnt(0)" ::: "memory");
      ST_AGENT(xpflag_p, t + 1);
    }
  }
}

// ---------------------------------------------------------------------------
// Consumer, XP mode: recurrence only, xpart streamed from producers
// ---------------------------------------------------------------------------
template<bool FAST>
__device__ __forceinline__ void run_lstm_xp(
    const float* __restrict__ h0, const float* __restrict__ c0,
    float* __restrict__ out, int* flagsT, int* flagsBT, int* xpflag_p,
    unsigned short* __restrict__ hring, unsigned short* __restrict__ lring,
    const f32x4* ringW, int win,
    const bf16x8* Ahi, const bf16x8* Alo,   // 16 h-part frag pairs
    int tid, int lane, int wg, int quad, int myb, int myh)
{
  float c_st  = c0[myb * NH + myh];
  float h_val = 0.0f;
  const int mask = win - 1;

  // wait for xp(0), then fetch it (waitcnt inside the asm -> value is ready)
  int xpf = 0;
  while (xpf < 1) {
    xpf = LD_AGENT(xpflag_p);
    if (xpf < 1) __builtin_amdgcn_s_sleep(1);
  }
  f32x4 xp_cur;
  asm volatile("global_load_dwordx4 %0, %1, off sc0 sc1\n\ts_waitcnt vmcnt(0)"
               : "=&v"(xp_cur) : "v"(ringW + lane) : "memory");

#pragma unroll 1
  for (int t = 0; t < NS; ++t) {
    f32x4 a_hh = {0.f, 0.f, 0.f, 0.f};
    f32x4 a_hl = {0.f, 0.f, 0.f, 0.f};
    f32x4 a_lh = {0.f, 0.f, 0.f, 0.f};

    if (t > 0) {
      int spin = 0;
      while (true) {
        int fl;
        if (FAST) {
          fl = poll_sc0(flagsT + lane);
          if ((++spin & 8191) == 0) {            // watchdog via L3 copy
            int fb = LD_AGENT(flagsBT + lane);
            if (fb > fl) fl = fb;
          }
        } else {
          fl = LD_AGENT(flagsT + lane);
        }
        unsigned int d = (unsigned int)(fl - FLAG_MAGIC);
        if (__all(d >= (unsigned int)t && d <= 512u)) break;
        __builtin_amdgcn_s_sleep(1);
      }
      asm volatile("" ::: "memory");
    }

    // prefetch xpart(t+1): issue now, consumed only after the vmcnt(0) +
    // sched_barrier(0) at the bottom of this step (rule-18 discipline)
    f32x4 xp_nxt;
    const bool pf = (t + 1 < NS);
    if (pf) {
      if (xpf < t + 2) {
        while (true) {
          xpf = LD_AGENT(xpflag_p);
          if (xpf >= t + 2) break;
          __builtin_amdgcn_s_sleep(1);
        }
      }
      const f32x4* p = ringW + (size_t)((t + 1) & mask) * 64 + lane;
      asm volatile("global_load_dwordx4 %0, %1, off sc0 sc1"
                   : "=&v"(xp_nxt) : "v"(p) : "memory");
    }

    if (t > 0) {
      const unsigned short* hbp = hring + (t - 1) * PLANE_ELEMS + myb * NH + quad * 8;
      const unsigned short* lbp = lring + (t - 1) * PLANE_ELEMS + myb * NH + quad * 8;
#pragma unroll
      for (int half = 0; half < 2; ++half) {
        Frag bh[8], bl[8];
#pragma unroll
        for (int c = 0; c < 8; ++c) {          // batch: 16 loads in flight
          int off = (half * 8 + c) * 32;
          bh[c].v = *(const bf16x8*)(hbp + off);
          bl[c].v = *(const bf16x8*)(lbp + off);
        }
#pragma unroll
        for (int c = 0; c < 8; ++c) {
          int w = half * 8 + c;
          a_hh = MFMA(Ahi[w], bh[c].v, a_hh);
          a_hl = MFMA(Ahi[w], bl[c].v, a_hl);
          a_lh = MFMA(Alo[w], bh[c].v, a_lh);
        }
      }
    } else {
      const float* hr = h0 + myb * NH + quad * 8;
#pragma unroll
      for (int c = 0; c < 16; ++c) {
        float4 f0 = *(const float4*)(hr + 32 * c);
        float4 f1 = *(const float4*)(hr + 32 * c + 4);
        float vals[8] = {f0.x, f0.y, f0.z, f0.w, f1.x, f1.y, f1.z, f1.w};
        Frag bh, bl;
        hilo8(vals, bh, bl);
        a_hh = MFMA(Ahi[c], bh.v, a_hh);
        a_hl = MFMA(Ahi[c], bl.v, a_hl);
        a_lh = MFMA(Alo[c], bh.v, a_lh);
      }
    }

    // LSTM cell: preact = streamed xpart + h part
    float pre_i = xp_cur[0] + a_hh[0] + a_hl[0] + a_lh[0];
    float pre_f = xp_cur[1] + a_hh[1] + a_hl[1] + a_lh[1];
    float pre_g = xp_cur[2] + a_hh[2] + a_hl[2] + a_lh[2];
    float pre_o = xp_cur[3] + a_hh[3] + a_hl[3] + a_lh[3];
    float gi = fsigmoid(pre_i);
    float gf = fsigmoid(pre_f);
    float gg = ftanh(pre_g);
    float go = fsigmoid(pre_o);
    c_st  = gf * c_st + gi * gg;
    h_val = go * ftanh(c_st);

    // publish h_t (hi/lo bf16, packed u32 per h-pair)
    __bf16 hh = (__bf16)h_val;
    float  rr = h_val - bf2f(hh);
    __bf16 hl = (__bf16)rr;
    unsigned int uh = (unsigned int)__builtin_bit_cast(unsigned short, hh);
    unsigned int ul = (unsigned int)__builtin_bit_cast(unsigned short, hl);
    unsigned int ph = (unsigned int)__shfl_xor((int)uh, 16, 64);
    unsigned int pl = (unsigned int)__shfl_xor((int)ul, 16, 64);
    if ((quad & 1) == 0) {
      int eoff = t * PLANE_ELEMS + myb * NH + myh;
      if (FAST) {
        ST_WG((unsigned int*)(hring + eoff), uh | (ph << 16));
        ST_WG((unsigned int*)(lring + eoff), ul | (pl << 16));
      } else {
        ST_AGENT((unsigned int*)(hring + eoff), uh | (ph << 16));
        ST_AGENT((unsigned int*)(lring + eoff), ul | (pl << 16));
      }
    }

    // drain h stores AND the xp prefetch; nothing may cross this point
    asm volatile("s_waitcnt vmcnt(0)" ::: "memory");
    __builtin_amdgcn_sched_barrier(0);
    __syncthreads();
    if (tid == 0) {
      if (FAST) {
        ST_WG(flagsT + wg, FLAG_MAGIC + t + 1);
      } else {
        ST_AGENT(flagsT + wg, FLAG_MAGIC + t + 1);
      }
      ST_AGENT(flagsBT + wg, FLAG_MAGIC + t + 1);  // producers pace off this
    }

    out[(myb * NS + t) * NH + myh] = h_val;
    if (pf) xp_cur = xp_nxt;   // after vmcnt(0)+sched_barrier: value is valid
  }

  const int obase = NB * NS * NH;
  out[obase + myb * NH + myh] = h_val;
  out[obase + NB * NH + myb * NH + myh] = c_st;
}

// ---------------------------------------------------------------------------
// Consumer, inline fallback (R5 path; used when win == 0)
// ---------------------------------------------------------------------------
template<bool FAST>
__device__ __forceinline__ void run_lstm_inline(
    const float* __restrict__ x, const float* __restrict__ h0,
    const float* __restrict__ c0, float* __restrict__ out,
    int* flagsT, int* flagsBT,
    unsigned short* __restrict__ hring, unsigned short* __restrict__ lring,
    const bf16x8* Ahi, const bf16x8* Alo, const float* bias,
    int tid, int lane, int wg, int quad, int myb, int myh)
{
  float c_st  = c0[myb * NH + myh];
  float h_val = 0.0f;

#pragma unroll 1
  for (int t = 0; t < NS; ++t) {
    float4 xf[16];
    const float* xr = x + (myb * NS + t) * ND + quad * 8;
#pragma unroll
    for (int c = 0; c < 8; ++c) {
      xf[2 * c]     = *(const float4*)(xr + 32 * c);
      xf[2 * c + 1] = *(const float4*)(xr + 32 * c + 4);
    }
    f32x4 a_hh = {bias[0], bias[1], bias[2], bias[3]};
    f32x4 a_hl = {0.f, 0.f, 0.f, 0.f};
    f32x4 a_lh = {0.f, 0.f, 0.f, 0.f};
#pragma unroll
    for (int c = 0; c < 8; ++c) {
      float vals[8] = {xf[2*c].x, xf[2*c].y, xf[2*c].z, xf[2*c].w,
                       xf[2*c+1].x, xf[2*c+1].y, xf[2*c+1].z, xf[2*c+1].w};
      Frag bh, bl;
      hilo8(vals, bh, bl);
      a_hh = MFMA(Ahi[c], bh.v, a_hh);
      a_hl = MFMA(Ahi[c], bl.v, a_hl);
      a_lh = MFMA(Alo[c], bh.v, a_lh);
    }

    if (t > 0) {
      int spin = 0;
      while (true) {
        int fl;
        if (FAST) {
          fl = poll_sc0(flagsT + lane);
          if ((++spin & 8191) == 0) {
            int fb = LD_AGENT(flagsBT + lane);
            if (fb > fl) fl = fb;
          }
        } else {
          fl = LD_AGENT(flagsT + lane);
        }
        unsigned int d = (unsigned int)(fl - FLAG_MAGIC);
        if (__all(d >= (unsigned int)t && d <= 512u)) break;
        __builtin_amdgcn_s_sleep(1);
      }
      asm volatile("" ::: "memory");

      const unsigned short* hbp = hring + (t - 1) * PLANE_ELEMS + myb * NH + quad * 8;
      const unsigned short* lbp = lring + (t - 1) * PLANE_ELEMS + myb * NH + quad * 8;
#pragma unroll
      for (int c = 8; c < 24; ++c) {
        int off = 32 * (c - 8);
        Frag bh, bl;
        bh.v = *(const bf16x8*)(hbp + off);
        bl.v = *(const bf16x8*)(lbp + off);
        a_hh = MFMA(Ahi[c], bh.v, a_hh);
        a_hl = MFMA(Ahi[c], bl.v, a_hl);
        a_lh = MFMA(Alo[c], bh.v, a_lh);
      }
    } else {
      const float* hr = h0 + myb * NH + quad * 8;
#pragma unroll
      for (int c = 8; c < 24; ++c) {
        int off = 32 * (c - 8);
        float4 f0 = *(const float4*)(hr + off);
        float4 f1 = *(const float4*)(hr + off + 4);
        float vals[8] = {f0.x, f0.y, f0.z, f0.w, f1.x, f1.y, f1.z, f1.w};
        Frag bh, bl;
        hilo8(vals, bh, bl);
        a_hh = MFMA(Ahi[c], bh.v, a_hh);
        a_hl = MFMA(Ahi[c], bl.v, a_hl);
        a_lh = MFMA(Alo[c], bh.v, a_lh);
      }
    }

    float pre_i = a_hh[0] + a_hl[0] + a_lh[0];
    float pre_f = a_hh[1] + a_hl[1] + a_lh[1];
    float pre_g = a_hh[2] + a_hl[2] + a_lh[2];
    float pre_o = a_hh[3] + a_hl[3] + a_lh[3];
    float gi = fsigmoid(pre_i);
    float gf = fsigmoid(pre_f);
    float gg = ftanh(pre_g);
    float go = fsigmoid(pre_o);
    c_st  = gf * c_st + gi * gg;
    h_val = go * ftanh(c_st);

    __bf16 hh = (__bf16)h_val;
    float  rr = h_val - bf2f(hh);
    __bf16 hl = (__bf16)rr;
    unsigned int uh = (unsigned int)__builtin_bit_cast(unsigned short, hh);
    unsigned int ul = (unsigned int)__builtin_bit_cast(unsigned short, hl);
    unsigned int ph = (unsigned int)__shfl_xor((int)uh, 16, 64);
    unsigned int pl = (unsigned int)__shfl_xor((int)ul, 16, 64);
    if ((quad & 1) == 0) {
      int eoff = t * PLANE_ELEMS + myb * NH + myh;
      if (FAST) {
        ST_WG((unsigned int*)(hring + eoff), uh | (ph << 16));
        ST_WG((unsigned int*)(lring + eoff), ul | (pl << 16));
      } else {
        ST_AGENT((unsigned int*)(hring + eoff), uh | (ph << 16));
        ST_AGENT((unsigned int*)(lring + eoff), ul | (pl << 16));
      }
    }

    asm volatile("s_waitcnt vmcnt(0)" ::: "memory");
    __syncthreads();
    if (tid == 0) {
      if (FAST) {
        ST_WG(flagsT + wg, FLAG_MAGIC + t + 1);
      } else {
        ST_AGENT(flagsT + wg, FLAG_MAGIC + t + 1);
      }
      ST_AGENT(flagsBT + wg, FLAG_MAGIC + t + 1);
    }

    out[(myb * NS + t) * NH + myh] = h_val;
  }

  const int obase = NB * NS * NH;
  out[obase + myb * NH + myh] = h_val;
  out[obase + NB * NH + myb * NH + myh] = c_st;
}

// ---------------------------------------------------------------------------
__global__ __launch_bounds__(128, 1)
void lstm_pc(const float* __restrict__ x,
             const float* __restrict__ Wih,
             const float* __restrict__ Whh,
             const float* __restrict__ bih,
             const float* __restrict__ bhh,
             const float* __restrict__ h0,
             const float* __restrict__ c0,
             float* __restrict__ out,
             int* flags, int* flagsB, int* ready, unsigned int* masks,
             int* xpflags,
             unsigned short* __restrict__ hring,
             unsigned short* __restrict__ lring,
             f32x4* __restrict__ xpring, int win)
{
  const int b    = blockIdx.x;
  const int role = (b >> 2) & 1;  // b%8 in {4..7} -> producer
  const int team = b & 3;
  const int wg   = b >> 3;
  const int tid  = threadIdx.x;
  const int lane = tid & 63;
  const int wv   = tid >> 6;
  const int l15  = lane & 15;
  const int quad = lane >> 4;
  const int hb   = wg * 8 + wv * 4;
  const int myb  = team * 16 + l15;
  const int myh  = hb + quad;
  const int jA   = l15 >> 2;
  const int gA   = l15 & 3;
  const int rA   = gA * NH + hb + jA;
  const int wslot = (team * 64 + wg) * 2 + wv;

  if (role == 1) {
    if (win > 0)
      run_producer(x, Wih, bih, bhh, flagsB + team * 64 + wg, xpflags + wslot,
                   xpring + (size_t)wslot * win * 64, win,
                   lane, quad, myb, myh, rA);
    return;
  }

  int* flagsT  = flags  + team * 64;
  int* flagsBT = flagsB + team * 64;

  // placement handshake (consumers only)
  int xcc;
  asm volatile("s_getreg_b32 %0, hwreg(HW_REG_XCC_ID)" : "=s"(xcc));
  if (tid == 0) {
    __hip_atomic_fetch_or(&masks[team], 1u << (xcc & 31),
                          __ATOMIC_RELAXED, __HIP_MEMORY_SCOPE_AGENT);
    __hip_atomic_fetch_add(ready, 1, __ATOMIC_RELEASE, __HIP_MEMORY_SCOPE_AGENT);
  }

  // persistent weights (overlaps handshake)
  bf16x8 Ahi[24], Alo[24];
  float bias[4] = {0.f, 0.f, 0.f, 0.f};
  if (win > 0) {
    const float* wh = Whh + rA * NH;
#pragma unroll
    for (int c = 0; c < 16; ++c) {
      int k0 = c * 32 + quad * 8;
      float4 f0 = *(const float4*)(wh + k0);
      float4 f1 = *(const float4*)(wh + k0 + 4);
      float vals[8] = {f0.x, f0.y, f0.z, f0.w, f1.x, f1.y, f1.z, f1.w};
      Frag fh, fl;
      hilo8(vals, fh, fl);
      Ahi[c] = fh.v;
      Alo[c] = fl.v;
    }
  } else {
    const float* wi = Wih + rA * ND;
    const float* wh = Whh + rA * NH;
#pragma unroll
    for (int c = 0; c < 24; ++c) {
      int k0 = c * 32 + quad * 8;
      const float* src = (c < 8) ? (wi + k0) : (wh + (k0 - 256));
      float4 f0 = *(const float4*)(src);
      float4 f1 = *(const float4*)(src + 4);
      float vals[8] = {f0.x, f0.y, f0.z, f0.w, f1.x, f1.y, f1.z, f1.w};
      Frag fh, fl;
      hilo8(vals, fh, fl);
      Ahi[c] = fh.v;
      Alo[c] = fl.v;
    }
#pragma unroll
    for (int g = 0; g < 4; ++g)
      bias[g] = bih[g * NH + myh] + bhh[g * NH + myh];
  }

  // finish handshake: fast iff the whole team saw ONE xcc_id
  __shared__ int s_fast;
  if (tid == 0) {
    while (__hip_atomic_load(ready, __ATOMIC_ACQUIRE,
                             __HIP_MEMORY_SCOPE_AGENT) < NWORK)
      __builtin_amdgcn_s_sleep(2);
    unsigned int m = LD_AGENT(&masks[team]);
    s_fast = (__popc(m) == 1) ? 1 : 0;
  }
  __syncthreads();

  if (win > 0) {
    const f32x4* ringW = xpring + (size_t)wslot * win * 64;
    if (s_fast)
      run_lstm_xp<true>(h0, c0, out, flagsT, flagsBT, xpflags + wslot,
                        hring, lring, ringW, win, Ahi, Alo,
                        tid, lane, wg, quad, myb, myh);
    else
      run_lstm_xp<false>(h0, c0, out, flagsT, flagsBT, xpflags + wslot,
                         hring, lring, ringW, win, Ahi, Alo,
                         tid, lane, wg, quad, myb, myh);
  } else {
    if (s_fast)
      run_lstm_inline<true>(x, h0, c0, out, flagsT, flagsBT, hring, lring,
                            Ahi, Alo, bias, tid, lane, wg, quad, myb, myh);
    else
      run_lstm_inline<false>(x, h0, c0, out, flagsT, flagsBT, hring, lring,
                             Ahi, Alo, bias, tid, lane, wg, quad, myb, myh);
  }
}

extern "C" void kernel_launch(void* const* d_in, const int* in_sizes, int n_in,
                              void* d_out, int out_size, void* d_ws, size_t ws_size,
                              hipStream_t stream) {
  const float* x   = (const float*)d_in[0];
  const float* Wih = (const float*)d_in[1];
  const float* Whh = (const float*)d_in[2];
  const float* bih = (const float*)d_in[3];
  const float* bhh = (const float*)d_in[4];
  const float* h0  = (const float*)d_in[5];
  const float* c0  = (const float*)d_in[6];
  float* out = (float*)d_out;

  char* ws = (char*)d_ws;
  // layout: [0,1024) flags | [1024] ready | [1028,1044) masks |
  //         [2048,3072) flagsB | [4096,6144) xpflags |
  //         [8192,+33.55MB) hring | +33.55MB lring | then xpring
  int* flags  = (int*)ws;
  int* ready  = (int*)(ws + 1024);
  unsigned int* masks = (unsigned int*)(ws + 1028);
  int* flagsB = (int*)(ws + 2048);
  int* xpflags = (int*)(ws + 4096);
  const size_t ringBytes = (size_t)NS * PLANE_ELEMS * sizeof(unsigned short);
  unsigned short* hring = (unsigned short*)(ws + 8192);
  unsigned short* lring = (unsigned short*)(ws + 8192 + ringBytes);
  const size_t baseNeed = 8192 + 2 * ringBytes;       // ~67.1 MB
  f32x4* xpring = (f32x4*)(ws + baseNeed);

  int win = 0;
  for (int w = 64; w >= 8; w >>= 1) {
    if (baseNeed + (size_t)512 * w * 1024 <= ws_size) { win = w; break; }
  }

  (void)hipMemsetAsync(ws, 0, 8192, stream);

  lstm_pc<<<dim3(512), dim3(128), 0, stream>>>(
      x, Wih, Whh, bih, bhh, h0, c0, out, flags, flagsB, ready, masks,
      xpflags, hring, lring, xpring, win);
}

// Round 4
// 4802.227 us; speedup vs baseline: 117.0751x; 117.0751x over previous
//
#include <hip/hip_runtime.h>

// Persistent-LSTM, round 8: R5 base + out[] store moved OFF the serial chain.
//   B=64,S=512,D=256,H=512. 4 teams x 16 batches; team = 64 WGs x 128 thr.
//   Wave owns 16 gate rows (4 h-idx x 4 gates), W hi/lo bf16 resident.
//   gates = [x_t,h_{t-1}] @ W^T via mfma_f32_16x16x32_bf16 (compensated hi/lo).
//
//   R7 post-mortem: producer/consumer split degenerated to watchdog-paced
//   progress (1.1ms/step = 8192 spins x ~300cy). Reverted to R5 base.
//   R3 vs R5 evidence: sync scope AND data locality changed massively
//   (FETCH 399->62MB), dur flat -> the ~8.6us/step stall is scope-invariant.
//   The one scope-invariant multi-us term in the chain: the scattered 4B
//   out[] HBM stores, drained EVERY STEP by the next poll's embedded
//   s_waitcnt vmcnt(0) (HBM store ack ~1-3us). R8 single change: h_val is
//   buffered in LDS (s_out[64][128], thread-local slots, no extra syncs)
//   and flushed in bulk every 64 steps AFTER the flag store -- the per-step
//   drain then covers only the two 4B h-ring stores (L2 ack in FAST mode).

#define NB 64
#define NS 512
#define ND 256
#define NH 512
#define FLAG_MAGIC 0x41000000
#define PLANE_ELEMS (NB * NH)   // 32768 elems, 64 KiB/plane
#define NWORK 256               // worker blocks: 4 teams x 64 WGs

typedef __bf16 bf16x8 __attribute__((ext_vector_type(8)));
typedef float  f32x4  __attribute__((ext_vector_type(4)));

union Frag {
  bf16x8 v;
  unsigned long long u[2];
  __bf16 e[8];
};

__device__ __forceinline__ float bf2f(__bf16 b) {
  unsigned short us = __builtin_bit_cast(unsigned short, b);
  unsigned int ui = ((unsigned int)us) << 16;
  return __builtin_bit_cast(float, ui);
}

__device__ __forceinline__ void hilo8(const float* vals, Frag& fh, Frag& fl) {
#pragma unroll
  for (int j = 0; j < 8; ++j) {
    __bf16 hi = (__bf16)vals[j];
    float r = vals[j] - bf2f(hi);
    fh.e[j] = hi;
    fl.e[j] = (__bf16)r;
  }
}

__device__ __forceinline__ float fsigmoid(float x) {
  return 1.0f / (1.0f + __expf(-x));
}
__device__ __forceinline__ float ftanh(float x) {
  float t = fminf(fmaxf(2.0f * x, -30.0f), 30.0f);
  float e = __expf(t);
  return (e - 1.0f) / (e + 1.0f);
}

// L1-bypass load served by the XCD L2 (the coherence point vs plain stores
// from other CUs on the SAME XCD). gfx950 spelling: sc0.
__device__ __forceinline__ int poll_sc0(const int* p) {
  int v;
  asm volatile("global_load_dword %0, %1, off sc0\n\ts_waitcnt vmcnt(0)"
               : "=&v"(v) : "v"(p) : "memory");
  return v;
}

template<bool FAST>
__device__ __forceinline__ void run_lstm(
    const float* __restrict__ x, const float* __restrict__ h0,
    const float* __restrict__ c0, float* __restrict__ out,
    int* flagsT, int* flagsBT,
    unsigned short* __restrict__ hring, unsigned short* __restrict__ lring,
    const bf16x8* Ahi, const bf16x8* Alo, const float* bias,
    float (*s_out)[128],
    int tid, int lane, int wg, int quad, int myb, int myh)
{
  float c_st  = c0[myb * NH + myh];
  float h_val = 0.0f;

#pragma unroll 1
  for (int t = 0; t < NS; ++t) {
    // ---- x-projection partial: bias + x_t @ Wih^T (drained before poll) ---
    float4 xf[16];
    const float* xr = x + (myb * NS + t) * ND + quad * 8;
#pragma unroll
    for (int c = 0; c < 8; ++c) {
      xf[2 * c]     = *(const float4*)(xr + 32 * c);
      xf[2 * c + 1] = *(const float4*)(xr + 32 * c + 4);
    }
    f32x4 a_hh = {bias[0], bias[1], bias[2], bias[3]};
    f32x4 a_hl = {0.f, 0.f, 0.f, 0.f};
    f32x4 a_lh = {0.f, 0.f, 0.f, 0.f};
#pragma unroll
    for (int c = 0; c < 8; ++c) {
      float vals[8] = {xf[2*c].x, xf[2*c].y, xf[2*c].z, xf[2*c].w,
                       xf[2*c+1].x, xf[2*c+1].y, xf[2*c+1].z, xf[2*c+1].w};
      Frag bh, bl;
      hilo8(vals, bh, bl);
      a_hh = __builtin_amdgcn_mfma_f32_16x16x32_bf16(Ahi[c], bh.v, a_hh, 0, 0, 0);
      a_hl = __builtin_amdgcn_mfma_f32_16x16x32_bf16(Ahi[c], bl.v, a_hl, 0, 0, 0);
      a_lh = __builtin_amdgcn_mfma_f32_16x16x32_bf16(Alo[c], bh.v, a_lh, 0, 0, 0);
    }

    // ---- h recurrence -----------------------------------------------------
    if (t > 0) {
      // wait for all 64 team WGs to finish step t-1
      int spin = 0;
      while (true) {
        int fl;
        if (FAST) {
          fl = poll_sc0(flagsT + lane);          // XCD-L2 hit
          if ((++spin & 8191) == 0) {            // watchdog: L3 backup copy
            int fb = __hip_atomic_load(flagsBT + lane, __ATOMIC_RELAXED,
                                       __HIP_MEMORY_SCOPE_AGENT);
            if (fb > fl) fl = fb;
          }
        } else {
          fl = __hip_atomic_load(flagsT + lane, __ATOMIC_RELAXED,
                                 __HIP_MEMORY_SCOPE_AGENT);
        }
        unsigned int d = (unsigned int)(fl - FLAG_MAGIC);
        if (__all(d >= (unsigned int)t && d <= 512u)) break;
        __builtin_amdgcn_s_sleep(1);
      }
      asm volatile("" ::: "memory");  // no h load hoisted above the poll

      // fresh addresses each step -> plain loads are coherent
      const unsigned short* hbp = hring + (t - 1) * PLANE_ELEMS + myb * NH + quad * 8;
      const unsigned short* lbp = lring + (t - 1) * PLANE_ELEMS + myb * NH + quad * 8;
#pragma unroll
      for (int c = 8; c < 24; ++c) {
        int off = 32 * (c - 8);
        Frag bh, bl;
        bh.v = *(const bf16x8*)(hbp + off);
        bl.v = *(const bf16x8*)(lbp + off);
        a_hh = __builtin_amdgcn_mfma_f32_16x16x32_bf16(Ahi[c], bh.v, a_hh, 0, 0, 0);
        a_hl = __builtin_amdgcn_mfma_f32_16x16x32_bf16(Ahi[c], bl.v, a_hl, 0, 0, 0);
        a_lh = __builtin_amdgcn_mfma_f32_16x16x32_bf16(Alo[c], bh.v, a_lh, 0, 0, 0);
      }
    } else {
      const float* hr = h0 + myb * NH + quad * 8;
#pragma unroll
      for (int c = 8; c < 24; ++c) {
        int off = 32 * (c - 8);
        float4 f0 = *(const float4*)(hr + off);
        float4 f1 = *(const float4*)(hr + off + 4);
        float vals[8] = {f0.x, f0.y, f0.z, f0.w, f1.x, f1.y, f1.z, f1.w};
        Frag bh, bl;
        hilo8(vals, bh, bl);
        a_hh = __builtin_amdgcn_mfma_f32_16x16x32_bf16(Ahi[c], bh.v, a_hh, 0, 0, 0);
        a_hl = __builtin_amdgcn_mfma_f32_16x16x32_bf16(Ahi[c], bl.v, a_hl, 0, 0, 0);
        a_lh = __builtin_amdgcn_mfma_f32_16x16x32_bf16(Alo[c], bh.v, a_lh, 0, 0, 0);
      }
    }

    // ---- LSTM cell (lane-local) -------------------------------------------
    float pre_i = a_hh[0] + a_hl[0] + a_lh[0];
    float pre_f = a_hh[1] + a_hl[1] + a_lh[1];
    float pre_g = a_hh[2] + a_hl[2] + a_lh[2];
    float pre_o = a_hh[3] + a_hl[3] + a_lh[3];
    float gi = fsigmoid(pre_i);
    float gf = fsigmoid(pre_f);
    float gg = ftanh(pre_g);
    float go = fsigmoid(pre_o);
    c_st  = gf * c_st + gi * gg;
    h_val = go * ftanh(c_st);

    // ---- R8: stage h into LDS (thread-local slot; no HBM store in chain) --
    s_out[t & 63][tid] = h_val;

    // ---- publish h_t (hi/lo bf16, packed u32 per h-pair) --------------------
    __bf16 hh = (__bf16)h_val;
    float  rr = h_val - bf2f(hh);
    __bf16 hl = (__bf16)rr;
    unsigned int uh = (unsigned int)__builtin_bit_cast(unsigned short, hh);
    unsigned int ul = (unsigned int)__builtin_bit_cast(unsigned short, hl);
    unsigned int ph = (unsigned int)__shfl_xor((int)uh, 16, 64);
    unsigned int pl = (unsigned int)__shfl_xor((int)ul, 16, 64);
    if ((quad & 1) == 0) {
      int eoff = t * PLANE_ELEMS + myb * NH + myh;
      if (FAST) {
        __hip_atomic_store((unsigned int*)(hring + eoff), uh | (ph << 16),
                           __ATOMIC_RELAXED, __HIP_MEMORY_SCOPE_WORKGROUP);
        __hip_atomic_store((unsigned int*)(lring + eoff), ul | (pl << 16),
                           __ATOMIC_RELAXED, __HIP_MEMORY_SCOPE_WORKGROUP);
      } else {
        __hip_atomic_store((unsigned int*)(hring + eoff), uh | (ph << 16),
                           __ATOMIC_RELAXED, __HIP_MEMORY_SCOPE_AGENT);
        __hip_atomic_store((unsigned int*)(lring + eoff), ul | (pl << 16),
                           __ATOMIC_RELAXED, __HIP_MEMORY_SCOPE_AGENT);
      }
    }

    // order h stores (L2 ack in FAST, L3 ack in slow) before the flag.
    // With out[] gone, this drains ONLY the two 4B ring stores.
    asm volatile("s_waitcnt vmcnt(0)" ::: "memory");
    __syncthreads();
    if (tid == 0) {
      if (FAST) {
        __hip_atomic_store(flagsT + wg, FLAG_MAGIC + t + 1,
                           __ATOMIC_RELAXED, __HIP_MEMORY_SCOPE_WORKGROUP);
        __hip_atomic_store(flagsBT + wg, FLAG_MAGIC + t + 1,
                           __ATOMIC_RELAXED, __HIP_MEMORY_SCOPE_AGENT);
      } else {
        __hip_atomic_store(flagsT + wg, FLAG_MAGIC + t + 1,
                           __ATOMIC_RELAXED, __HIP_MEMORY_SCOPE_AGENT);
      }
    }

    // ---- bulk flush every 64 steps, AFTER the flag (off teammates' path;
    //      only my own next poll waits for it, once per 64 steps) ----------
    if ((t & 63) == 63) {
      int t0 = t - 63;
      // each thread flushes its own 64 staged values; the 4 quads of one
      // l15 write 4 consecutive floats -> HW-coalesced 16B transactions
#pragma unroll 4
      for (int ti = 0; ti < 64; ++ti)
        out[(myb * NS + t0 + ti) * NH + myh] = s_out[ti][tid];
    }
  }

  const int obase = NB * NS * NH;
  out[obase + myb * NH + myh] = h_val;
  out[obase + NB * NH + myb * NH + myh] = c_st;
}

__global__ __launch_bounds__(128, 1)
void lstm_l2(const float* __restrict__ x,
             const float* __restrict__ Wih,
             const float* __restrict__ Whh,
             const float* __restrict__ bih,
             const float* __restrict__ bhh,
             const float* __restrict__ h0,
             const float* __restrict__ c0,
             float* __restrict__ out,
             int* flags, int* flagsB, int* ready, unsigned int* masks,
             unsigned short* __restrict__ hring,
             unsigned short* __restrict__ lring)
{
  const int b = blockIdx.x;
  if ((b & 7) >= 4) return;       // shadow blocks: fill XCDs 4-7's round-robin
  const int team = b & 7;         // 0..3 -> one XCD per team (if mapping holds)
  const int wg   = b >> 3;        // 0..63
  const int tid  = threadIdx.x;
  const int lane = tid & 63;
  const int wv   = tid >> 6;
  const int l15  = lane & 15;
  const int quad = lane >> 4;
  const int hb   = wg * 8 + wv * 4;
  const int myb  = team * 16 + l15;
  const int myh  = hb + quad;

  int* flagsT  = flags  + team * 64;
  int* flagsBT = flagsB + team * 64;

  // ---- placement handshake (one-time): which XCD is this block on? --------
  int xcc;
  asm volatile("s_getreg_b32 %0, hwreg(HW_REG_XCC_ID)" : "=s"(xcc));
  if (tid == 0) {
    __hip_atomic_fetch_or(&masks[team], 1u << (xcc & 31),
                          __ATOMIC_RELAXED, __HIP_MEMORY_SCOPE_AGENT);
    __hip_atomic_fetch_add(ready, 1, __ATOMIC_RELEASE, __HIP_MEMORY_SCOPE_AGENT);
  }

  // ---- persistent A operand: W rows, compensated hi/lo (overlaps handshake)
  const int jA = l15 >> 2;
  const int gA = l15 & 3;
  const int rA = gA * NH + hb + jA;
  bf16x8 Ahi[24], Alo[24];
  {
    const float* wi = Wih + rA * ND;
    const float* wh = Whh + rA * NH;
#pragma unroll
    for (int c = 0; c < 24; ++c) {
      int k0 = c * 32 + quad * 8;
      const float* src = (c < 8) ? (wi + k0) : (wh + (k0 - 256));
      float4 f0 = *(const float4*)(src);
      float4 f1 = *(const float4*)(src + 4);
      float vals[8] = {f0.x, f0.y, f0.z, f0.w, f1.x, f1.y, f1.z, f1.w};
      Frag fh, fl;
      hilo8(vals, fh, fl);
      Ahi[c] = fh.v;
      Alo[c] = fl.v;
    }
  }

  float bias[4];
#pragma unroll
  for (int g = 0; g < 4; ++g)
    bias[g] = bih[g * NH + myh] + bhh[g * NH + myh];

  // ---- R8: 32KB LDS staging for out[] (thread-local slots) ----------------
  __shared__ float s_out[64][128];

  // ---- finish handshake: fast iff my whole team saw ONE xcc_id ------------
  __shared__ int s_fast;
  if (tid == 0) {
    while (__hip_atomic_load(ready, __ATOMIC_ACQUIRE,
                             __HIP_MEMORY_SCOPE_AGENT) < NWORK)
      __builtin_amdgcn_s_sleep(2);
    unsigned int m = __hip_atomic_load(&masks[team], __ATOMIC_RELAXED,
                                       __HIP_MEMORY_SCOPE_AGENT);
    s_fast = (__popc(m) == 1) ? 1 : 0;
  }
  __syncthreads();

  if (s_fast)
    run_lstm<true>(x, h0, c0, out, flagsT, flagsBT, hring, lring,
                   Ahi, Alo, bias, s_out, tid, lane, wg, quad, myb, myh);
  else
    run_lstm<false>(x, h0, c0, out, flagsT, flagsBT, hring, lring,
                    Ahi, Alo, bias, s_out, tid, lane, wg, quad, myb, myh);
}

extern "C" void kernel_launch(void* const* d_in, const int* in_sizes, int n_in,
                              void* d_out, int out_size, void* d_ws, size_t ws_size,
                              hipStream_t stream) {
  const float* x   = (const float*)d_in[0];
  const float* Wih = (const float*)d_in[1];
  const float* Whh = (const float*)d_in[2];
  const float* bih = (const float*)d_in[3];
  const float* bhh = (const float*)d_in[4];
  const float* h0  = (const float*)d_in[5];
  const float* c0  = (const float*)d_in[6];
  float* out = (float*)d_out;

  char* ws = (char*)d_ws;
  // layout: [0,1024) flags  [1024] ready  [1028,1044) masks  [2048,3072) flagsB
  //         [4096, +33.5MB) hring  [.., +33.5MB) lring   (~67.1 MB total)
  int* flags  = (int*)ws;
  int* ready  = (int*)(ws + 1024);
  unsigned int* masks = (unsigned int*)(ws + 1028);
  int* flagsB = (int*)(ws + 2048);
  const size_t ringBytes = (size_t)NS * PLANE_ELEMS * sizeof(unsigned short);
  unsigned short* hring = (unsigned short*)(ws + 4096);
  unsigned short* lring = (unsigned short*)(ws + 4096 + ringBytes);

  // zero flag page each launch: kills cross-launch flag/counter staleness
  (void)hipMemsetAsync(ws, 0, 4096, stream);

  lstm_l2<<<dim3(512), dim3(128), 0, stream>>>(
      x, Wih, Whh, bih, bhh, h0, c0, out, flags, flagsB, ready, masks,
      hring, lring);
}